// Round 4
// baseline (11501.598 us; speedup 1.0000x reference)
//
#include <hip/hip_runtime.h>
#include <hip/hip_bf16.h>
#include <float.h>
#include <math.h>

#define BN   4096
#define DD   112
#define HH   512
#define G3   1536
#define CW   536
#define HIDD 512

typedef __attribute__((ext_vector_type(8))) short short8;
typedef __attribute__((ext_vector_type(4))) float float4v;

__device__ __forceinline__ unsigned short f2bf(float x) {
    __hip_bfloat16 h = __float2bfloat16(x);
    return *(unsigned short*)&h;
}

// ---------------- materialize const = [c | b | m]  (B x 536) ----------------
__global__ void build_const(const float* __restrict__ c, const float* __restrict__ b,
                            const float* __restrict__ m, float* __restrict__ out) {
    int idx = blockIdx.x * blockDim.x + threadIdx.x;
    if (idx >= BN * CW) return;
    int row = idx / CW, col = idx - row * CW;
    float v;
    if (col < 312)      v = c[row * 312 + col];
    else if (col < 424) v = b[row * 112 + (col - 312)];
    else                v = m[row * 112 + (col - 424)];
    out[idx] = v;
}

// ---------------- gi_const GEMM -> packed per-(block,wave,lane) C-layout ----------------
// gicP[(((b*8+w)*4+i)*2+mt)*3+g][lane][rg]  (float4 per lane)
__global__ __launch_bounds__(256) void gemm_gic(const float* __restrict__ A,
        const float* __restrict__ W, const float* __restrict__ bih,
        const float* __restrict__ bhh, float* __restrict__ gicP) {
    const int N = G3;
    __shared__ float As[8][64];
    __shared__ float Ws[8][64];
    const int tid = threadIdx.x;
    const int tx = tid & 15, ty = tid >> 4;
    const int rowBase = blockIdx.x * 64, colBase = blockIdx.y * 64;
    float acc[4][4] = {};
    for (int kb = 0; kb < CW; kb += 8) {
        int l = tid * 2;
        {
            int i = l >> 3, j = l & 7;
            As[j][i] = A[(rowBase + i) * CW + kb + j];
            int i2 = (l + 1) >> 3, j2 = (l + 1) & 7;
            As[j2][i2] = A[(rowBase + i2) * CW + kb + j2];
        }
        {
            int j = l >> 6, n = l & 63;
            Ws[j][n] = W[(kb + j) * N + colBase + n];
            int j2 = (l + 1) >> 6, n2 = (l + 1) & 63;
            Ws[j2][n2] = W[(kb + j2) * N + colBase + n2];
        }
        __syncthreads();
#pragma unroll
        for (int k = 0; k < 8; ++k) {
            float av[4], wv[4];
#pragma unroll
            for (int i = 0; i < 4; ++i) av[i] = As[k][ty * 4 + i];
#pragma unroll
            for (int j = 0; j < 4; ++j) wv[j] = Ws[k][tx * 4 + j];
#pragma unroll
            for (int i = 0; i < 4; ++i)
#pragma unroll
                for (int j = 0; j < 4; ++j) acc[i][j] += av[i] * wv[j];
        }
        __syncthreads();
    }
#pragma unroll
    for (int i = 0; i < 4; ++i) {
        int r = rowBase + ty * 4 + i;
        int bb = r >> 5, mrem = r & 31, mt = mrem >> 4, q4 = mrem & 15;
        int laneHi = (q4 >> 2) << 4, rg = q4 & 3;
#pragma unroll
        for (int j = 0; j < 4; ++j) {
            int cc = colBase + tx * 4 + j;
            int g = cc >> 9, crem = cc & 511, tile = crem >> 4, l16 = crem & 15;
            int w = tile & 7, ii = tile >> 3;
            size_t off = ((((size_t)(bb * 8 + w) * 4 + ii) * 2 + mt) * 3 + g) * 256
                         + (laneHi + l16) * 4 + rg;
            float v = acc[i][j] + bih[cc] + ((g < 2) ? bhh[cc] : 0.0f);
            gicP[off] = v;
        }
    }
}

// ---------------- mlp_const GEMM -> packed layout ----------------
__global__ __launch_bounds__(256) void gemm_mlc(const float* __restrict__ A,
        const float* __restrict__ W, const float* __restrict__ b0,
        float* __restrict__ mlcP) {
    const int N = HIDD;
    __shared__ float As[8][64];
    __shared__ float Ws[8][64];
    const int tid = threadIdx.x;
    const int tx = tid & 15, ty = tid >> 4;
    const int rowBase = blockIdx.x * 64, colBase = blockIdx.y * 64;
    float acc[4][4] = {};
    for (int kb = 0; kb < CW; kb += 8) {
        int l = tid * 2;
        {
            int i = l >> 3, j = l & 7;
            As[j][i] = A[(rowBase + i) * CW + kb + j];
            int i2 = (l + 1) >> 3, j2 = (l + 1) & 7;
            As[j2][i2] = A[(rowBase + i2) * CW + kb + j2];
        }
        {
            int j = l >> 6, n = l & 63;
            Ws[j][n] = W[(kb + j) * N + colBase + n];
            int j2 = (l + 1) >> 6, n2 = (l + 1) & 63;
            Ws[j2][n2] = W[(kb + j2) * N + colBase + n2];
        }
        __syncthreads();
#pragma unroll
        for (int k = 0; k < 8; ++k) {
            float av[4], wv[4];
#pragma unroll
            for (int i = 0; i < 4; ++i) av[i] = As[k][ty * 4 + i];
#pragma unroll
            for (int j = 0; j < 4; ++j) wv[j] = Ws[k][tx * 4 + j];
#pragma unroll
            for (int i = 0; i < 4; ++i)
#pragma unroll
                for (int j = 0; j < 4; ++j) acc[i][j] += av[i] * wv[j];
        }
        __syncthreads();
    }
#pragma unroll
    for (int i = 0; i < 4; ++i) {
        int r = rowBase + ty * 4 + i;
        int bb = r >> 5, mrem = r & 31, mt = mrem >> 4, q4 = mrem & 15;
        int laneHi = (q4 >> 2) << 4, rg = q4 & 3;
#pragma unroll
        for (int j = 0; j < 4; ++j) {
            int cc = colBase + tx * 4 + j;
            int tile = cc >> 4, l16 = cc & 15;
            int w = tile & 7, ii = tile >> 3;
            size_t off = (((size_t)(bb * 8 + w) * 4 + ii) * 2 + mt) * 256
                         + (laneHi + l16) * 4 + rg;
            mlcP[off] = acc[i][j] + b0[cc];
        }
    }
}

// ---------------- mask = descending sort of m*(1-b) per row ----------------
__global__ void sort_mask(const float* __restrict__ b, const float* __restrict__ m,
                          float* __restrict__ maskbuf) {
    __shared__ float s[128];
    const int row = blockIdx.x, t = threadIdx.x;
    float v = -FLT_MAX;
    if (t < DD) v = m[row * DD + t] * (1.0f - b[row * DD + t]);
    s[t] = v;
    __syncthreads();
    for (int k = 2; k <= 128; k <<= 1) {
        for (int j = k >> 1; j > 0; j >>= 1) {
            int ixj = t ^ j;
            if (ixj > t) {
                bool up = ((t & k) == 0);
                float a = s[t], bb = s[ixj];
                if ((a > bb) == up) { s[t] = bb; s[ixj] = a; }
            }
            __syncthreads();
        }
    }
    if (t < DD) maskbuf[row * DD + t] = s[127 - t];
}

// ---------------- pack weight [K][N] -> MFMA B-fragments ----------------
__global__ void pack_w(const float* __restrict__ src, unsigned short* __restrict__ dst,
                       int kchunks, int ldn, int ncols) {
    int bid = blockIdx.x;
    int nt = bid / kchunks, kc = bid - nt * kchunks;
    int lane = threadIdx.x;
    int quad = lane >> 4, l16 = lane & 15;
    int n = nt * 16 + l16;
    unsigned short v[8];
#pragma unroll
    for (int j = 0; j < 8; ++j) {
        int k = kc * 32 + quad * 8 + j;
        float f = (n < ncols) ? src[(size_t)k * ldn + n] : 0.0f;
        v[j] = f2bf(f);
    }
    unsigned short* p = dst + ((size_t)bid * 64 + lane) * 8;
#pragma unroll
    for (int j = 0; j < 8; ++j) p[j] = v[j];
}

// ---------------- persistent GRU + MLP head + MDN logp (bf16 MFMA, M=32) ----------------
// 128 blocks x 32 rows, 512 threads = 8 waves. Each weight frag reused for 2 m-tiles.
__global__ __launch_bounds__(512, 2) void gru_mfma(
    const float* __restrict__ z, const float* __restrict__ Wih,
    const float* __restrict__ bhh, const float* __restrict__ b1,
    const float* __restrict__ b2,
    const float* __restrict__ gicP, const float* __restrict__ mlcP,
    const float* __restrict__ maskbuf,
    const unsigned short* __restrict__ WhhP, const unsigned short* __restrict__ W0hP,
    const unsigned short* __restrict__ W1P, const unsigned short* __restrict__ W2P,
    float* __restrict__ out)
{
    __shared__ unsigned short h_bf[32 * 520];  // bf16 mirror of h (fp32 master in regs)
    __shared__ unsigned short a_bf[32 * 520];  // a1 then a2
    __shared__ float pp[8 * 1024];             // W2 K-partials: [wave][mt*2+nt][lane][rg]

    const int tid = threadIdx.x;
    const int wave = tid >> 6, lane = tid & 63;
    const int quad = lane >> 4, l16 = lane & 15;
    const int pr = tid >> 5, pc = tid & 31;
    const int rowBase = blockIdx.x * 32;

    for (int idx = tid; idx < 32 * 520; idx += 512) h_bf[idx] = 0;

    int hcol[4];
    float wz0[4], wz1[4], wz2[4], bh2r[4], b1c[4];
#pragma unroll
    for (int i = 0; i < 4; ++i) {
        int hc = (wave + 8 * i) * 16 + l16;
        hcol[i] = hc;
        wz0[i] = Wih[hc]; wz1[i] = Wih[512 + hc]; wz2[i] = Wih[1024 + hc];
        bh2r[i] = bhh[1024 + hc];
        b1c[i] = b1[hc];
    }
    float h_own[4][2][4];
#pragma unroll
    for (int i = 0; i < 4; ++i)
#pragma unroll
        for (int mt = 0; mt < 2; ++mt)
#pragma unroll
            for (int rg = 0; rg < 4; ++rg) h_own[i][mt][rg] = 0.0f;

    const float b2v = (pc < 30) ? b2[pc] : 0.0f;
    const float* gicW = gicP + (size_t)(blockIdx.x * 8 + wave) * 4 * 2 * 3 * 256;
    const float* mlcW = mlcP + (size_t)(blockIdx.x * 8 + wave) * 4 * 2 * 256;

    const short8* WhhF = (const short8*)WhhP;
    const short8* W0hF = (const short8*)W0hP;
    const short8* W1F  = (const short8*)W1P;
    const short8* W2F  = (const short8*)W2P;

    float llacc0 = 0.0f, llacc1 = 0.0f;
    __syncthreads();

    for (int t = 0; t < DD; ++t) {
        // prefetch z_prev for owned rows (hidden behind gates MFMA)
        float zp[2][4];
#pragma unroll
        for (int mt = 0; mt < 2; ++mt)
#pragma unroll
            for (int rg = 0; rg < 4; ++rg) {
                int m = mt * 16 + quad * 4 + rg;
                zp[mt][rg] = (t == 0) ? -1.0f : z[(size_t)(rowBase + m) * DD + t - 1];
            }
        // ---- gates: h @ Whh, acc init from packed gi_const (L2-hot dwordx4) ----
        float4v acc[3][4][2];
#pragma unroll
        for (int i = 0; i < 4; ++i)
#pragma unroll
            for (int mt = 0; mt < 2; ++mt) {
                acc[0][i][mt] = *(const float4v*)(gicW + ((i * 2 + mt) * 3 + 0) * 256 + lane * 4);
                acc[1][i][mt] = *(const float4v*)(gicW + ((i * 2 + mt) * 3 + 1) * 256 + lane * 4);
                acc[2][i][mt] = (float4v){0.f, 0.f, 0.f, 0.f};
            }
#pragma unroll 2
        for (int kc = 0; kc < 16; ++kc) {
            short8 af[2];
#pragma unroll
            for (int mt = 0; mt < 2; ++mt)
                af[mt] = *(const short8*)&h_bf[(mt * 16 + l16) * 520 + kc * 32 + quad * 8];
#pragma unroll
            for (int i = 0; i < 4; ++i) {
                int tile = wave + 8 * i;
#pragma unroll
                for (int g = 0; g < 3; ++g) {
                    short8 bf = WhhF[((tile + 32 * g) * 16 + kc) * 64 + lane];
#pragma unroll
                    for (int mt = 0; mt < 2; ++mt)
                        acc[g][i][mt] = __builtin_amdgcn_mfma_f32_16x16x32_bf16(af[mt], bf, acc[g][i][mt], 0, 0, 0);
                }
            }
        }
        __syncthreads();  // S1: all A-frag reads of h done
        // ---- GRU nonlinearity (fp32 register recurrence) ----
#pragma unroll
        for (int i = 0; i < 4; ++i) {
#pragma unroll
            for (int mt = 0; mt < 2; ++mt) {
                float4v gn = *(const float4v*)(gicW + ((i * 2 + mt) * 3 + 2) * 256 + lane * 4);
#pragma unroll
                for (int rg = 0; rg < 4; ++rg) {
                    int m = mt * 16 + quad * 4 + rg;
                    float zt = zp[mt][rg];
                    float r = 1.0f / (1.0f + __expf(-(acc[0][i][mt][rg] + zt * wz0[i])));
                    float u = 1.0f / (1.0f + __expf(-(acc[1][i][mt][rg] + zt * wz1[i])));
                    float xn = gn[rg] + zt * wz2[i] + r * (acc[2][i][mt][rg] + bh2r[i]);
                    float n = 1.0f - 2.0f / (__expf(2.0f * xn) + 1.0f);
                    float h2 = (1.0f - u) * n + u * h_own[i][mt][rg];
                    h_own[i][mt][rg] = h2;
                    h_bf[m * 520 + hcol[i]] = f2bf(h2);
                }
            }
        }
        __syncthreads();  // S2: h2 mirror ready
        // ---- a1 = tanh(h2 @ W0h + mlp_const) ----
        float4v a1[4][2];
#pragma unroll
        for (int i = 0; i < 4; ++i)
#pragma unroll
            for (int mt = 0; mt < 2; ++mt)
                a1[i][mt] = *(const float4v*)(mlcW + (i * 2 + mt) * 256 + lane * 4);
#pragma unroll 2
        for (int kc = 0; kc < 16; ++kc) {
            short8 af[2];
#pragma unroll
            for (int mt = 0; mt < 2; ++mt)
                af[mt] = *(const short8*)&h_bf[(mt * 16 + l16) * 520 + kc * 32 + quad * 8];
#pragma unroll
            for (int i = 0; i < 4; ++i) {
                short8 bf = W0hF[((wave + 8 * i) * 16 + kc) * 64 + lane];
#pragma unroll
                for (int mt = 0; mt < 2; ++mt)
                    a1[i][mt] = __builtin_amdgcn_mfma_f32_16x16x32_bf16(af[mt], bf, a1[i][mt], 0, 0, 0);
            }
        }
#pragma unroll
        for (int i = 0; i < 4; ++i)
#pragma unroll
            for (int mt = 0; mt < 2; ++mt)
#pragma unroll
                for (int rg = 0; rg < 4; ++rg) {
                    int m = mt * 16 + quad * 4 + rg;
                    float x = a1[i][mt][rg];
                    a_bf[m * 520 + hcol[i]] = f2bf(1.0f - 2.0f / (__expf(2.0f * x) + 1.0f));
                }
        __syncthreads();  // S3: a1 ready
        // ---- a2 = tanh(a1 @ W1 + b1) ----
        float4v a2[4][2];
#pragma unroll
        for (int i = 0; i < 4; ++i)
#pragma unroll
            for (int mt = 0; mt < 2; ++mt)
                a2[i][mt] = (float4v){b1c[i], b1c[i], b1c[i], b1c[i]};
#pragma unroll 2
        for (int kc = 0; kc < 16; ++kc) {
            short8 af[2];
#pragma unroll
            for (int mt = 0; mt < 2; ++mt)
                af[mt] = *(const short8*)&a_bf[(mt * 16 + l16) * 520 + kc * 32 + quad * 8];
#pragma unroll
            for (int i = 0; i < 4; ++i) {
                short8 bf = W1F[((wave + 8 * i) * 16 + kc) * 64 + lane];
#pragma unroll
                for (int mt = 0; mt < 2; ++mt)
                    a2[i][mt] = __builtin_amdgcn_mfma_f32_16x16x32_bf16(af[mt], bf, a2[i][mt], 0, 0, 0);
            }
        }
        __syncthreads();  // S4: all reads of a1 done
#pragma unroll
        for (int i = 0; i < 4; ++i)
#pragma unroll
            for (int mt = 0; mt < 2; ++mt)
#pragma unroll
                for (int rg = 0; rg < 4; ++rg) {
                    int m = mt * 16 + quad * 4 + rg;
                    float x = a2[i][mt][rg];
                    a_bf[m * 520 + hcol[i]] = f2bf(1.0f - 2.0f / (__expf(2.0f * x) + 1.0f));
                }
        __syncthreads();  // S5: a2 ready
        // ---- p = a2 @ W2 + b2 : K split across waves (2 kc each) ----
        {
            float4v ap[2][2];
#pragma unroll
            for (int mt = 0; mt < 2; ++mt)
#pragma unroll
                for (int nt = 0; nt < 2; ++nt) ap[mt][nt] = (float4v){0.f, 0.f, 0.f, 0.f};
#pragma unroll
            for (int kk = 0; kk < 2; ++kk) {
                int kc = wave * 2 + kk;
                short8 af[2];
#pragma unroll
                for (int mt = 0; mt < 2; ++mt)
                    af[mt] = *(const short8*)&a_bf[(mt * 16 + l16) * 520 + kc * 32 + quad * 8];
#pragma unroll
                for (int nt = 0; nt < 2; ++nt) {
                    short8 bf = W2F[(nt * 16 + kc) * 64 + lane];
#pragma unroll
                    for (int mt = 0; mt < 2; ++mt)
                        ap[mt][nt] = __builtin_amdgcn_mfma_f32_16x16x32_bf16(af[mt], bf, ap[mt][nt], 0, 0, 0);
                }
            }
#pragma unroll
            for (int mt = 0; mt < 2; ++mt)
#pragma unroll
                for (int nt = 0; nt < 2; ++nt)
#pragma unroll
                    for (int rg = 0; rg < 4; ++rg)
                        pp[wave * 1024 + (mt * 2 + nt) * 256 + lane * 4 + rg] = ap[mt][nt][rg];
        }
        __syncthreads();  // S6: partials ready
        // ---- reduce partials + MDN logsumexp, for both row halves ----
        const int ntv = pc >> 4, n_in = pc & 15;
        const int lane_c = (pr >> 2) * 16 + n_in, rgc = pr & 3;
#pragma unroll
        for (int rh = 0; rh < 2; ++rh) {
            float pv = b2v;
#pragma unroll
            for (int w = 0; w < 8; ++w)
                pv += pp[w * 1024 + (rh * 2 + ntv) * 256 + lane_c * 4 + rgc];
            const int half = lane & 32;
            float meanv = __shfl(pv, half + ((pc + 10) & 31), 64);
            float lsigv = __shfl(pv, half + ((pc + 20) & 31), 64);
            float e1, e2;
            if (pc < 10) {
                float ztar = z[(size_t)(rowBase + rh * 16 + pr) * DD + t];
                float invs = __expf(-lsigv);
                float dd = (ztar - meanv) * invs;
                e1 = -0.5f * dd * dd - lsigv - 0.91893853320467274f + pv;
                e2 = pv;
            } else { e1 = -FLT_MAX; e2 = -FLT_MAX; }
            float m1 = e1, m2 = e2;
#pragma unroll
            for (int off = 16; off > 0; off >>= 1) {
                m1 = fmaxf(m1, __shfl_xor(m1, off, 64));
                m2 = fmaxf(m2, __shfl_xor(m2, off, 64));
            }
            float s1 = (pc < 10) ? __expf(e1 - m1) : 0.0f;
            float s2 = (pc < 10) ? __expf(e2 - m2) : 0.0f;
#pragma unroll
            for (int off = 16; off > 0; off >>= 1) {
                s1 += __shfl_xor(s1, off, 64);
                s2 += __shfl_xor(s2, off, 64);
            }
            float ll = (m1 + __logf(s1)) - (m2 + __logf(s2));
            float mk = maskbuf[(size_t)(rowBase + rh * 16 + pr) * DD + t];
            if (rh == 0) llacc0 += ll * mk; else llacc1 += ll * mk;
        }
    }
    if (pc == 0) {
        out[rowBase + pr] = llacc0;
        out[rowBase + 16 + pr] = llacc1;
    }
}

extern "C" void kernel_launch(void* const* d_in, const int* in_sizes, int n_in,
                              void* d_out, int out_size, void* d_ws, size_t ws_size,
                              hipStream_t stream) {
    const float* z   = (const float*)d_in[0];
    const float* c   = (const float*)d_in[1];
    const float* b   = (const float*)d_in[2];
    const float* m   = (const float*)d_in[3];
    const float* Wih = (const float*)d_in[4];
    const float* Whh = (const float*)d_in[5];
    const float* bih = (const float*)d_in[6];
    const float* bhh = (const float*)d_in[7];
    const float* W0  = (const float*)d_in[8];
    const float* b0  = (const float*)d_in[9];
    const float* W1  = (const float*)d_in[10];
    const float* b1  = (const float*)d_in[11];
    const float* W2  = (const float*)d_in[12];
    const float* b2  = (const float*)d_in[13];
    float* out = (float*)d_out;

    float* ws        = (float*)d_ws;
    float* constbuf  = ws;                                   // B*536
    float* gicP      = constbuf + (size_t)BN * CW;           // B*1536 (packed)
    float* mlcP      = gicP + (size_t)BN * G3;               // B*512  (packed)
    float* maskbuf   = mlcP + (size_t)BN * HIDD;             // B*112
    unsigned short* WhhP = (unsigned short*)(maskbuf + (size_t)BN * DD);
    unsigned short* W0hP = WhhP + (size_t)96 * 16 * 512;
    unsigned short* W1P  = W0hP + (size_t)32 * 16 * 512;
    unsigned short* W2P  = W1P  + (size_t)32 * 16 * 512;

    build_const<<<(BN * CW + 255) / 256, 256, 0, stream>>>(c, b, m, constbuf);
    dim3 g1(BN / 64, G3 / 64);
    gemm_gic<<<g1, 256, 0, stream>>>(constbuf, Wih + G3, bih, bhh, gicP);
    dim3 g2(BN / 64, HIDD / 64);
    gemm_mlc<<<g2, 256, 0, stream>>>(constbuf, W0 + (size_t)HH * HIDD, b0, mlcP);
    sort_mask<<<BN, 128, 0, stream>>>(b, m, maskbuf);

    pack_w<<<96 * 16, 64, 0, stream>>>(Whh, WhhP, 16, G3, G3);
    pack_w<<<32 * 16, 64, 0, stream>>>(W0,  W0hP, 16, HIDD, HIDD);
    pack_w<<<32 * 16, 64, 0, stream>>>(W1,  W1P,  16, HIDD, HIDD);
    pack_w<<<2 * 16, 64, 0, stream>>>(W2,  W2P,  16, 30, 30);

    gru_mfma<<<BN / 32, 512, 0, stream>>>(z, Wih, bhh, b1, b2, gicP, mlcP,
                                          maskbuf, WhhP, W0hP, W1P, W2P, out);
}

// Round 5
// 3149.018 us; speedup vs baseline: 3.6524x; 3.6524x over previous
//
#include <hip/hip_runtime.h>
#include <hip/hip_bf16.h>
#include <float.h>
#include <math.h>

#define BN   4096
#define DD   112
#define HH   512
#define G3   1536
#define CW   536
#define HIDD 512

typedef __attribute__((ext_vector_type(8))) short short8;
typedef __attribute__((ext_vector_type(4))) float float4v;

__device__ __forceinline__ unsigned short f2bf(float x) {
    __hip_bfloat16 h = __float2bfloat16(x);
    return *(unsigned short*)&h;
}

// ---------------- materialize const = [c | b | m]  (B x 536) ----------------
__global__ void build_const(const float* __restrict__ c, const float* __restrict__ b,
                            const float* __restrict__ m, float* __restrict__ out) {
    int idx = blockIdx.x * blockDim.x + threadIdx.x;
    if (idx >= BN * CW) return;
    int row = idx / CW, col = idx - row * CW;
    float v;
    if (col < 312)      v = c[row * 312 + col];
    else if (col < 424) v = b[row * 112 + (col - 312)];
    else                v = m[row * 112 + (col - 424)];
    out[idx] = v;
}

// ---------------- C[M,N] = A[M,536] @ W[536,N] + bias, row-major (fp32 exact) ----------------
__global__ __launch_bounds__(256) void gemm_bias(const float* __restrict__ A,
        const float* __restrict__ W, const float* __restrict__ bias,
        float* __restrict__ C, int N) {
    __shared__ float As[8][64];
    __shared__ float Ws[8][64];
    const int tid = threadIdx.x;
    const int tx = tid & 15, ty = tid >> 4;
    const int rowBase = blockIdx.x * 64, colBase = blockIdx.y * 64;
    float acc[4][4] = {};
    for (int kb = 0; kb < CW; kb += 8) {
        int l = tid * 2;
        {
            int i = l >> 3, j = l & 7;
            As[j][i] = A[(rowBase + i) * CW + kb + j];
            int i2 = (l + 1) >> 3, j2 = (l + 1) & 7;
            As[j2][i2] = A[(rowBase + i2) * CW + kb + j2];
        }
        {
            int j = l >> 6, n = l & 63;
            Ws[j][n] = W[(kb + j) * N + colBase + n];
            int j2 = (l + 1) >> 6, n2 = (l + 1) & 63;
            Ws[j2][n2] = W[(kb + j2) * N + colBase + n2];
        }
        __syncthreads();
#pragma unroll
        for (int k = 0; k < 8; ++k) {
            float av[4], wv[4];
#pragma unroll
            for (int i = 0; i < 4; ++i) av[i] = As[k][ty * 4 + i];
#pragma unroll
            for (int j = 0; j < 4; ++j) wv[j] = Ws[k][tx * 4 + j];
#pragma unroll
            for (int i = 0; i < 4; ++i)
#pragma unroll
                for (int j = 0; j < 4; ++j) acc[i][j] += av[i] * wv[j];
        }
        __syncthreads();
    }
#pragma unroll
    for (int i = 0; i < 4; ++i) {
        int r = rowBase + ty * 4 + i;
#pragma unroll
        for (int j = 0; j < 4; ++j) {
            int cc = colBase + tx * 4 + j;
            C[r * N + cc] = acc[i][j] + bias[cc];
        }
    }
}

// ---------------- mask = descending sort of m*(1-b) per row ----------------
__global__ void sort_mask(const float* __restrict__ b, const float* __restrict__ m,
                          float* __restrict__ maskbuf) {
    __shared__ float s[128];
    const int row = blockIdx.x, t = threadIdx.x;
    float v = -FLT_MAX;
    if (t < DD) v = m[row * DD + t] * (1.0f - b[row * DD + t]);
    s[t] = v;
    __syncthreads();
    for (int k = 2; k <= 128; k <<= 1) {
        for (int j = k >> 1; j > 0; j >>= 1) {
            int ixj = t ^ j;
            if (ixj > t) {
                bool up = ((t & k) == 0);
                float a = s[t], bb = s[ixj];
                if ((a > bb) == up) { s[t] = bb; s[ixj] = a; }
            }
            __syncthreads();
        }
    }
    if (t < DD) maskbuf[row * DD + t] = s[127 - t];
}

// ---------------- pack weight [K][N] -> MFMA B-fragments ----------------
// frag(nt,kc): lane holds B[k=kc*32+quad*8+j][n=nt*16+(lane&15)], j=0..7
__global__ void pack_w(const float* __restrict__ src, unsigned short* __restrict__ dst,
                       int kchunks, int ldn, int ncols) {
    int bid = blockIdx.x;
    int nt = bid / kchunks, kc = bid - nt * kchunks;
    int lane = threadIdx.x;
    int quad = lane >> 4, l16 = lane & 15;
    int n = nt * 16 + l16;
    unsigned short v[8];
#pragma unroll
    for (int j = 0; j < 8; ++j) {
        int k = kc * 32 + quad * 8 + j;
        float f = (n < ncols) ? src[(size_t)k * ldn + n] : 0.0f;
        v[j] = f2bf(f);
    }
    unsigned short* p = dst + ((size_t)bid * 64 + lane) * 8;
#pragma unroll
    for (int j = 0; j < 8; ++j) p[j] = v[j];
}

// ---------------- persistent GRU + MLP head + MDN logp (bf16 MFMA) ----------------
// 256 blocks x 16 rows, 1024 threads = 16 waves (4/SIMD for load-latency hiding).
// Wave w owns n-tiles {w, w+16}. fp32 h master in regs; bf16 mirror in LDS.
__global__ __launch_bounds__(1024, 4) void gru_mfma(
    const float* __restrict__ z, const float* __restrict__ Wih,
    const float* __restrict__ bhh, const float* __restrict__ b1,
    const float* __restrict__ b2,
    const float* __restrict__ gi_const, const float* __restrict__ mlp_const,
    const float* __restrict__ maskbuf,
    const unsigned short* __restrict__ WhhP, const unsigned short* __restrict__ W0hP,
    const unsigned short* __restrict__ W1P, const unsigned short* __restrict__ W2P,
    float* __restrict__ out)
{
    __shared__ unsigned short h_bf[16 * 520];  // bf16 mirror of h (pad 520)
    __shared__ unsigned short a_bf[16 * 520];  // a1 then a2
    __shared__ float pp[16 * 512];             // W2 partials: [wave][nt][lane][rg]
    __shared__ float zbuf[113 * 16];           // zbuf[tt*16+r] = z_prev at step tt
    __shared__ float mbuf[16 * 112];           // mask per (row,t)

    const int tid = threadIdx.x;
    const int wave = tid >> 6, lane = tid & 63;
    const int quad = lane >> 4, l16 = lane & 15;
    const int pr = tid >> 5, pc = tid & 31;    // MDN mapping (waves 0..7 only)
    const int rowBase = blockIdx.x * 16;

    for (int idx = tid; idx < 16 * 520; idx += 1024) h_bf[idx] = 0;
    for (int idx = tid; idx < 113 * 16; idx += 1024) {
        int tt = idx >> 4, r = idx & 15;
        zbuf[idx] = (tt == 0) ? -1.0f : z[(rowBase + r) * DD + tt - 1];
    }
    for (int idx = tid; idx < 16 * 112; idx += 1024) {
        int r = idx / DD, tt = idx - r * DD;
        mbuf[idx] = maskbuf[(rowBase + r) * DD + tt];
    }

    // hoisted per-lane constants, C-layout (col = lane&15 within tile, row m = quad*4+rg)
    int hcol[2];
    float wz0[2], wz1[2], wz2[2], bh2r[2], b1c[2];
    float gic0[2][4], gic1[2][4], gic2[2][4], mlc[2][4];
    float h_own[2][4];  // fp32 master copy of h[m][hcol[i]]
#pragma unroll
    for (int i = 0; i < 2; ++i) {
        int tile = wave + 16 * i;
        int hc = tile * 16 + l16;
        hcol[i] = hc;
        wz0[i] = Wih[hc]; wz1[i] = Wih[512 + hc]; wz2[i] = Wih[1024 + hc];
        float bh0 = bhh[hc], bh1 = bhh[512 + hc];
        bh2r[i] = bhh[1024 + hc];
        b1c[i] = b1[hc];
#pragma unroll
        for (int rg = 0; rg < 4; ++rg) {
            int m = quad * 4 + rg;
            const float* g = gi_const + (size_t)(rowBase + m) * G3;
            gic0[i][rg] = g[hc] + bh0;
            gic1[i][rg] = g[512 + hc] + bh1;
            gic2[i][rg] = g[1024 + hc];
            mlc[i][rg] = mlp_const[(size_t)(rowBase + m) * HIDD + hc];
            h_own[i][rg] = 0.0f;
        }
    }
    const float b2v = (pc < 30) ? b2[pc] : 0.0f;
    const int ppbase = (pc >> 4) * 256 + ((pr >> 2) * 16 + (pc & 15)) * 4 + (pr & 3);

    const short8* WhhF = (const short8*)WhhP;
    const short8* W0hF = (const short8*)W0hP;
    const short8* W1F  = (const short8*)W1P;
    const short8* W2F  = (const short8*)W2P;

    float llacc = 0.0f;
    __syncthreads();

    for (int t = 0; t < DD; ++t) {
        // ---- gates: h @ Whh, 6 n-tiles/wave (2 per gate), C init = gi_const(+bhh) ----
        float4v accR[2], accU[2], accN[2];
#pragma unroll
        for (int i = 0; i < 2; ++i) {
            accR[i] = (float4v){gic0[i][0], gic0[i][1], gic0[i][2], gic0[i][3]};
            accU[i] = (float4v){gic1[i][0], gic1[i][1], gic1[i][2], gic1[i][3]};
            accN[i] = (float4v){0.f, 0.f, 0.f, 0.f};
        }
#pragma unroll 4
        for (int kc = 0; kc < 16; ++kc) {
            short8 af = *(const short8*)&h_bf[l16 * 520 + kc * 32 + quad * 8];
#pragma unroll
            for (int i = 0; i < 2; ++i) {
                int tile = wave + 16 * i;
                accR[i] = __builtin_amdgcn_mfma_f32_16x16x32_bf16(af, WhhF[(tile * 16 + kc) * 64 + lane], accR[i], 0, 0, 0);
                accU[i] = __builtin_amdgcn_mfma_f32_16x16x32_bf16(af, WhhF[((tile + 32) * 16 + kc) * 64 + lane], accU[i], 0, 0, 0);
                accN[i] = __builtin_amdgcn_mfma_f32_16x16x32_bf16(af, WhhF[((tile + 64) * 16 + kc) * 64 + lane], accN[i], 0, 0, 0);
            }
        }
        __syncthreads();  // S1: all A-frag reads of h done
        // ---- GRU nonlinearity (fp32 register recurrence) ----
#pragma unroll
        for (int i = 0; i < 2; ++i) {
#pragma unroll
            for (int rg = 0; rg < 4; ++rg) {
                int m = quad * 4 + rg;
                float zt = zbuf[t * 16 + m];
                float r = 1.0f / (1.0f + __expf(-(accR[i][rg] + zt * wz0[i])));
                float u = 1.0f / (1.0f + __expf(-(accU[i][rg] + zt * wz1[i])));
                float xn = gic2[i][rg] + zt * wz2[i] + r * (accN[i][rg] + bh2r[i]);
                float n = 1.0f - 2.0f / (__expf(2.0f * xn) + 1.0f);
                float h2 = (1.0f - u) * n + u * h_own[i][rg];
                h_own[i][rg] = h2;
                h_bf[m * 520 + hcol[i]] = f2bf(h2);
            }
        }
        __syncthreads();  // S2: h2 mirror ready
        // ---- a1 = tanh(h2 @ W0h + mlp_const) ----
        float4v acc1[2];
#pragma unroll
        for (int i = 0; i < 2; ++i) acc1[i] = (float4v){mlc[i][0], mlc[i][1], mlc[i][2], mlc[i][3]};
#pragma unroll 4
        for (int kc = 0; kc < 16; ++kc) {
            short8 af = *(const short8*)&h_bf[l16 * 520 + kc * 32 + quad * 8];
#pragma unroll
            for (int i = 0; i < 2; ++i)
                acc1[i] = __builtin_amdgcn_mfma_f32_16x16x32_bf16(af, W0hF[((wave + 16 * i) * 16 + kc) * 64 + lane], acc1[i], 0, 0, 0);
        }
#pragma unroll
        for (int i = 0; i < 2; ++i)
#pragma unroll
            for (int rg = 0; rg < 4; ++rg) {
                int m = quad * 4 + rg;
                float x = acc1[i][rg];
                a_bf[m * 520 + hcol[i]] = f2bf(1.0f - 2.0f / (__expf(2.0f * x) + 1.0f));
            }
        __syncthreads();  // S3: a1 ready
        // ---- a2 = tanh(a1 @ W1 + b1) ----
        float4v acc2[2];
#pragma unroll
        for (int i = 0; i < 2; ++i) acc2[i] = (float4v){b1c[i], b1c[i], b1c[i], b1c[i]};
#pragma unroll 4
        for (int kc = 0; kc < 16; ++kc) {
            short8 af = *(const short8*)&a_bf[l16 * 520 + kc * 32 + quad * 8];
#pragma unroll
            for (int i = 0; i < 2; ++i)
                acc2[i] = __builtin_amdgcn_mfma_f32_16x16x32_bf16(af, W1F[((wave + 16 * i) * 16 + kc) * 64 + lane], acc2[i], 0, 0, 0);
        }
        __syncthreads();  // S4: all reads of a1 done
#pragma unroll
        for (int i = 0; i < 2; ++i)
#pragma unroll
            for (int rg = 0; rg < 4; ++rg) {
                int m = quad * 4 + rg;
                float x = acc2[i][rg];
                a_bf[m * 520 + hcol[i]] = f2bf(1.0f - 2.0f / (__expf(2.0f * x) + 1.0f));
            }
        __syncthreads();  // S5: a2 ready
        // ---- p = a2 @ W2 + b2 : K split across 16 waves (1 kc each), 2 n-tiles ----
        {
            int kc = wave;
            short8 af = *(const short8*)&a_bf[l16 * 520 + kc * 32 + quad * 8];
            float4v ap0 = (float4v){0.f, 0.f, 0.f, 0.f}, ap1 = (float4v){0.f, 0.f, 0.f, 0.f};
            ap0 = __builtin_amdgcn_mfma_f32_16x16x32_bf16(af, W2F[(0 * 16 + kc) * 64 + lane], ap0, 0, 0, 0);
            ap1 = __builtin_amdgcn_mfma_f32_16x16x32_bf16(af, W2F[(1 * 16 + kc) * 64 + lane], ap1, 0, 0, 0);
#pragma unroll
            for (int rg = 0; rg < 4; ++rg) {
                pp[wave * 512 + 0 * 256 + lane * 4 + rg] = ap0[rg];
                pp[wave * 512 + 1 * 256 + lane * 4 + rg] = ap1[rg];
            }
        }
        __syncthreads();  // S6: partials ready
        // ---- reduce partials + MDN logsumexp (waves 0..7 = rows 0..15) ----
        if (wave < 8) {
            float pv = b2v;
#pragma unroll
            for (int w = 0; w < 16; ++w) pv += pp[w * 512 + ppbase];
            const int half = lane & 32;
            float meanv = __shfl(pv, half + ((pc + 10) & 31), 64);
            float lsigv = __shfl(pv, half + ((pc + 20) & 31), 64);
            float e1, e2;
            if (pc < 10) {
                float ztar = zbuf[(t + 1) * 16 + pr];
                float invs = __expf(-lsigv);
                float dd = (ztar - meanv) * invs;
                e1 = -0.5f * dd * dd - lsigv - 0.91893853320467274f + pv;
                e2 = pv;
            } else { e1 = -FLT_MAX; e2 = -FLT_MAX; }
            float m1 = e1, m2 = e2;
#pragma unroll
            for (int off = 16; off > 0; off >>= 1) {
                m1 = fmaxf(m1, __shfl_xor(m1, off, 64));
                m2 = fmaxf(m2, __shfl_xor(m2, off, 64));
            }
            float s1 = (pc < 10) ? __expf(e1 - m1) : 0.0f;
            float s2 = (pc < 10) ? __expf(e2 - m2) : 0.0f;
#pragma unroll
            for (int off = 16; off > 0; off >>= 1) {
                s1 += __shfl_xor(s1, off, 64);
                s2 += __shfl_xor(s2, off, 64);
            }
            float ll = (m1 + __logf(s1)) - (m2 + __logf(s2));
            llacc += ll * mbuf[pr * 112 + t];
        }
    }
    if (wave < 8 && pc == 0) out[rowBase + pr] = llacc;
}

extern "C" void kernel_launch(void* const* d_in, const int* in_sizes, int n_in,
                              void* d_out, int out_size, void* d_ws, size_t ws_size,
                              hipStream_t stream) {
    const float* z   = (const float*)d_in[0];
    const float* c   = (const float*)d_in[1];
    const float* b   = (const float*)d_in[2];
    const float* m   = (const float*)d_in[3];
    const float* Wih = (const float*)d_in[4];
    const float* Whh = (const float*)d_in[5];
    const float* bih = (const float*)d_in[6];
    const float* bhh = (const float*)d_in[7];
    const float* W0  = (const float*)d_in[8];
    const float* b0  = (const float*)d_in[9];
    const float* W1  = (const float*)d_in[10];
    const float* b1  = (const float*)d_in[11];
    const float* W2  = (const float*)d_in[12];
    const float* b2  = (const float*)d_in[13];
    float* out = (float*)d_out;

    float* ws        = (float*)d_ws;
    float* constbuf  = ws;                                   // B*536
    float* gi_const  = constbuf + (size_t)BN * CW;           // B*1536
    float* mlp_const = gi_const + (size_t)BN * G3;           // B*512
    float* maskbuf   = mlp_const + (size_t)BN * HIDD;        // B*112
    unsigned short* WhhP = (unsigned short*)(maskbuf + (size_t)BN * DD);
    unsigned short* W0hP = WhhP + (size_t)96 * 16 * 512;
    unsigned short* W1P  = W0hP + (size_t)32 * 16 * 512;
    unsigned short* W2P  = W1P  + (size_t)32 * 16 * 512;

    build_const<<<(BN * CW + 255) / 256, 256, 0, stream>>>(c, b, m, constbuf);
    dim3 g1(BN / 64, G3 / 64);
    gemm_bias<<<g1, 256, 0, stream>>>(constbuf, Wih + G3, bih, gi_const, G3);
    dim3 g2(BN / 64, HIDD / 64);
    gemm_bias<<<g2, 256, 0, stream>>>(constbuf, W0 + (size_t)HH * HIDD, b0, mlp_const, HIDD);
    sort_mask<<<BN, 128, 0, stream>>>(b, m, maskbuf);

    pack_w<<<96 * 16, 64, 0, stream>>>(Whh, WhhP, 16, G3, G3);
    pack_w<<<32 * 16, 64, 0, stream>>>(W0,  W0hP, 16, HIDD, HIDD);
    pack_w<<<32 * 16, 64, 0, stream>>>(W1,  W1P,  16, HIDD, HIDD);
    pack_w<<<2 * 16, 64, 0, stream>>>(W2,  W2P,  16, 30, 30);

    gru_mfma<<<BN / 16, 1024, 0, stream>>>(z, Wih, bhh, b1, b2, gi_const, mlp_const,
                                           maskbuf, WhhP, W0hP, W1P, W2P, out);
}